// Round 4
// baseline (238.579 us; speedup 1.0000x reference)
//
#include <hip/hip_runtime.h>
#include <stdint.h>

#define BATCH 256
#define IN_F  1024
#define OUT_F 1024
#define RT    16      // row tiles (IN_F/64)
#define STN   16      // input bit-streams
#define NCOL  16384   // 16 (sg,s) groups * 1024 outputs

typedef int v4i  __attribute__((ext_vector_type(4)));
typedef int v16i __attribute__((ext_vector_type(16)));

// ws layout: Ap2 4MB | Bp 16MB | Part 16MB | flags 512B
#define AP_SZ   ((size_t)STN * BATCH * IN_F)
#define BP_SZ   ((size_t)64 * NCOL * 16)
#define PART_SZ ((size_t)16 * BATCH * OUT_F * sizeof(float))

// ---------------------------------------------------------------------------
// A in MFMA-fragment order: chunk index (t, r, f) holds, for b-block y,
// 64 lanes x 16 bytes where lane l = (k16&1)*32 + (b&31), bytes = bits t of
// x_int[b][r*64 + f*32 + (l>>5)*16 + j].  Main kernel loads af as one
// coalesced 1KB global_load_dwordx4 per wave.  Item = (kg, b): quantize x
// once, emit 16 t-planes.
// ---------------------------------------------------------------------------
__global__ __launch_bounds__(256) void pack_A(const float* __restrict__ x,
                                              uint8_t* __restrict__ Ap2,
                                              uint32_t* __restrict__ flags) {
    if (blockIdx.x == 0 && threadIdx.x < 128) flags[threadIdx.x] = 0;
    int item = blockIdx.x * 256 + threadIdx.x;      // 16384 items
    int b  = item & 255;
    int kg = item >> 8;                             // 16-elem k-group 0..63
    int r = kg >> 2, f = (kg >> 1) & 1, hi = kg & 1;
    int y = b >> 5, l = hi * 32 + (b & 31);
    const float* xr = x + (size_t)b * IN_F + kg * 16;
    uint32_t xu[16];
    #pragma unroll
    for (int j = 0; j < 16; ++j) {
        float xf = rintf(xr[j] * 4096.0f);          // round half-even
        xf = fminf(fmaxf(xf, -32768.0f), 32767.0f);
        xu[j] = (uint32_t)((int)xf) & 0xFFFFu;      // two's complement low 16
    }
    #pragma unroll
    for (int t = 0; t < STN; ++t) {
        uint32_t dw[4];
        #pragma unroll
        for (int q = 0; q < 4; ++q) {
            uint32_t d = 0;
            #pragma unroll
            for (int j = 0; j < 4; ++j)
                d |= ((xu[q * 4 + j] >> t) & 1u) << (8 * j);
            dw[q] = d;
        }
        *(uint4*)(Ap2 + ((size_t)(((t * RT + r) * 2 + f) * 8 + y) * 1024 + l * 16)) =
            make_uint4(dw[0], dw[1], dw[2], dw[3]);
    }
}

// ---------------------------------------------------------------------------
// B_packed[g][c][16], c = (sg*8+s)*1024 + o.  One item per (g,o): quantize w
// once, emit all 16 (sg,s) slice vectors (writes coalesced over o).
// Sets flags[sgs*8+ob] bit r if any slice byte in the (128-o x 64-k) tile
// is nonzero (o>>7 and g>>2 wave-uniform).
// ---------------------------------------------------------------------------
__global__ __launch_bounds__(256) void pack_B(const float* __restrict__ w,
                                              uint8_t* __restrict__ Bp,
                                              uint32_t* __restrict__ flags) {
    int item = blockIdx.x * 256 + threadIdx.x;      // 65536 items
    int o = item & 1023;
    int g = item >> 10;                             // 0..63
    const float* wr = w + (size_t)o * IN_F + g * 16;
    uint32_t wq[2][16];
    #pragma unroll
    for (int j = 0; j < 16; ++j) {
        float wv = wr[j];
        float wp = rintf(fmaxf(wv, 0.0f) * 4096.0f);
        float wn = rintf(fmaxf(-wv, 0.0f) * 4096.0f);
        wq[0][j] = (uint32_t)fminf(wp, 65535.0f);
        wq[1][j] = (uint32_t)fminf(wn, 65535.0f);
    }
    uint32_t nzmask = 0;
    #pragma unroll
    for (int sgs = 0; sgs < 16; ++sgs) {
        int sg = sgs >> 3, sh = 14 - 2 * (sgs & 7);
        uint32_t dw[4], nz = 0;
        #pragma unroll
        for (int q = 0; q < 4; ++q) {
            uint32_t d = 0;
            #pragma unroll
            for (int j = 0; j < 4; ++j)
                d |= ((wq[sg][q * 4 + j] >> sh) & 3u) << (8 * j);
            dw[q] = d;
            nz |= d;
        }
        *(uint4*)(Bp + (size_t)(g * NCOL + sgs * 1024 + o) * 16) =
            make_uint4(dw[0], dw[1], dw[2], dw[3]);
        nzmask |= (nz ? 1u : 0u) << sgs;
    }
    int r = g >> 2, ob = o >> 7;                    // wave-uniform
    #pragma unroll
    for (int sgs = 0; sgs < 16; ++sgs) {
        int any = __any((int)((nzmask >> sgs) & 1u));
        if (any && (threadIdx.x & 63) == 0)
            atomicOr(&flags[sgs * 8 + ob], 1u << r);
    }
}

// ---------------------------------------------------------------------------
// Main: block = 32 b x 128 col of one (sg,s) group; sgs interleaved across
// blockIdx.x for load balance.  No LDS: A fragments are direct coalesced
// global loads from the fragment-ordered Ap2 (L2-resident, 16x reuse).
// Per-(sgs,ob,r) flag skips all-zero B tiles exactly (ADC(0)=0).
// ADC bits identical to verified R1-R3: qf = rintf(a * 85/64) exact product;
// contribution qf * (+-step*4^(7-s)*2^t) with exact pow2 scales.
// ---------------------------------------------------------------------------
__global__ __launch_bounds__(256, 4) void cim_mfma(
    const uint8_t* __restrict__ Ap2, const uint8_t* __restrict__ Bp,
    const uint32_t* __restrict__ flags, float* __restrict__ part)
{
    int tid = threadIdx.x, wid = tid >> 6, l = tid & 63, h2 = l >> 5;
    int sgs = blockIdx.x & 15, ob = blockIdx.x >> 4;
    int y = blockIdx.y;
    int s = sgs & 7, sg = sgs >> 3;
    int col = sgs * 1024 + ob * 128 + wid * 32 + (l & 31);
    uint32_t fb = flags[sgs * 8 + ob];
    float clane = ldexpf(192.0f / 255.0f, 14 - 2 * s);
    if (sg) clane = -clane;

    float acc[16];
    #pragma unroll
    for (int i = 0; i < 16; ++i) acc[i] = 0.0f;
    v16i zero;
    #pragma unroll
    for (int i = 0; i < 16; ++i) zero[i] = 0;

    for (int r = 0; r < RT; ++r) {
        if (!((fb >> r) & 1u)) continue;            // uniform skip, exact

        v4i bf0 = *(const v4i*)(Bp + ((size_t)(r * 4 + h2)     * NCOL + col) * 16);
        v4i bf1 = *(const v4i*)(Bp + ((size_t)(r * 4 + 2 + h2) * NCOL + col) * 16);

        const uint8_t* abase = Ap2 + (size_t)(r * 2 * 8 + y) * 1024 + l * 16;
        #pragma unroll 4
        for (int t = 0; t < STN; ++t) {
            const uint8_t* ap = abase + (size_t)t * (RT * 2 * 8 * 1024);
            v4i af0 = *(const v4i*)ap;              // coalesced 1KB/wave
            v4i af1 = *(const v4i*)(ap + 8 * 1024);
            v16i c = __builtin_amdgcn_mfma_i32_32x32x32_i8(af0, bf0, zero, 0, 0, 0);
            c      = __builtin_amdgcn_mfma_i32_32x32x32_i8(af1, bf1, c,    0, 0, 0);
            float wt = (t == 15) ? -32768.0f : (float)(1 << t);
            float cw = clane * wt;                  // exact pow2 scale
            #pragma unroll
            for (int i = 0; i < 16; ++i) {
                float af = (float)c[i];             // v_cvt_f32_i32
                float qf = rintf(af * 1.328125f);   // round(a*85/64), half-even
                acc[i] = fmaf(qf, cw, acc[i]);
            }
        }
    }

    // unconditional partial write (zeros for skipped tiles)
    int o = ob * 128 + wid * 32 + (l & 31);
    #pragma unroll
    for (int i = 0; i < 16; ++i) {
        int b = blockIdx.y * 32 + (i & 3) + 8 * (i >> 2) + 4 * h2;  // C/D row map
        part[((size_t)sgs * BATCH + b) * OUT_F + o] = acc[i];
    }
}

// ---------------------------------------------------------------------------
__global__ __launch_bounds__(256) void reduce_out(
    const float* __restrict__ part, const float* __restrict__ bias,
    float* __restrict__ out)
{
    int idx = blockIdx.x * 256 + threadIdx.x;
    int o = idx & (OUT_F - 1), b = idx >> 10;
    float ov = 0.0f;
    #pragma unroll
    for (int sgs = 0; sgs < 16; ++sgs)
        ov += part[((size_t)sgs * BATCH + b) * OUT_F + o];
    ov *= 0x1p-24f;
    float q = rintf(ov * 4096.0f);
    q = fminf(fmaxf(q, -32768.0f), 32767.0f);
    out[idx] = q * 0x1p-12f + bias[o];
}

// ---------------------------------------------------------------------------
extern "C" void kernel_launch(void* const* d_in, const int* in_sizes, int n_in,
                              void* d_out, int out_size, void* d_ws, size_t ws_size,
                              hipStream_t stream) {
    const float* x    = (const float*)d_in[0];
    const float* w    = (const float*)d_in[1];
    const float* bias = (const float*)d_in[2];
    float* out = (float*)d_out;

    uint8_t*  Ap2   = (uint8_t*)d_ws;
    uint8_t*  Bp    = Ap2 + AP_SZ;
    float*    Part  = (float*)(Bp + BP_SZ);
    uint32_t* flags = (uint32_t*)((uint8_t*)Part + PART_SZ);

    hipLaunchKernelGGL(pack_A, dim3(64),  dim3(256), 0, stream, x, Ap2, flags);
    hipLaunchKernelGGL(pack_B, dim3(256), dim3(256), 0, stream, w, Bp, flags);
    hipLaunchKernelGGL(cim_mfma, dim3(128, 8), dim3(256), 0, stream,
                       Ap2, Bp, flags, Part);
    hipLaunchKernelGGL(reduce_out, dim3(BATCH * OUT_F / 256), dim3(256), 0, stream,
                       Part, bias, out);
}

// Round 5
// 222.595 us; speedup vs baseline: 1.0718x; 1.0718x over previous
//
#include <hip/hip_runtime.h>
#include <stdint.h>

#define BATCH 256
#define IN_F  1024
#define OUT_F 1024
#define RT    16      // row tiles (IN_F/64)
#define STN   16      // input bit-streams
#define NCOL  16384   // 16 (sg,s) groups * 1024 outputs

typedef int   v4i  __attribute__((ext_vector_type(4)));
typedef int   v16i __attribute__((ext_vector_type(16)));
typedef float v2f  __attribute__((ext_vector_type(2)));

// ws layout: Ap2 4MB | Bp 16MB | Part 16MB | flags 512B
#define AP_SZ   ((size_t)STN * BATCH * IN_F)
#define BP_SZ   ((size_t)64 * NCOL * 16)
#define PART_SZ ((size_t)16 * BATCH * OUT_F * sizeof(float))

// ---------------------------------------------------------------------------
// A in MFMA-fragment order (see R4).  Item = (kg, b): quantize once, emit 16
// t-planes.  Also zero-inits flags (consumed by the NEXT dispatch).
// ---------------------------------------------------------------------------
__global__ __launch_bounds__(256) void pack_A(const float* __restrict__ x,
                                              uint8_t* __restrict__ Ap2,
                                              uint32_t* __restrict__ flags) {
    if (blockIdx.x == 0 && threadIdx.x < 128) flags[threadIdx.x] = 0;
    int item = blockIdx.x * 256 + threadIdx.x;      // 16384 items
    int b  = item & 255;
    int kg = item >> 8;                             // 16-elem k-group 0..63
    int r = kg >> 2, f = (kg >> 1) & 1, hi = kg & 1;
    int y = b >> 5, l = hi * 32 + (b & 31);
    const float* xr = x + (size_t)b * IN_F + kg * 16;
    uint32_t xu[16];
    #pragma unroll
    for (int j = 0; j < 16; ++j) {
        float xf = rintf(xr[j] * 4096.0f);          // round half-even
        xf = fminf(fmaxf(xf, -32768.0f), 32767.0f);
        xu[j] = (uint32_t)((int)xf) & 0xFFFFu;      // two's complement low 16
    }
    #pragma unroll
    for (int t = 0; t < STN; ++t) {
        uint32_t dw[4];
        #pragma unroll
        for (int q = 0; q < 4; ++q) {
            uint32_t d = 0;
            #pragma unroll
            for (int j = 0; j < 4; ++j)
                d |= ((xu[q * 4 + j] >> t) & 1u) << (8 * j);
            dw[q] = d;
        }
        *(uint4*)(Ap2 + ((size_t)(((t * RT + r) * 2 + f) * 8 + y) * 1024 + l * 16)) =
            make_uint4(dw[0], dw[1], dw[2], dw[3]);
    }
}

// ---------------------------------------------------------------------------
// B_packed[g][c][16], c = (sg*8+s)*1024 + o.  One item per (g,o).
// flags[sgs*8+ob] bit r set iff the (128-o x 64-k) tile has any nonzero byte.
// ---------------------------------------------------------------------------
__global__ __launch_bounds__(256) void pack_B(const float* __restrict__ w,
                                              uint8_t* __restrict__ Bp,
                                              uint32_t* __restrict__ flags) {
    int item = blockIdx.x * 256 + threadIdx.x;      // 65536 items
    int o = item & 1023;
    int g = item >> 10;                             // 0..63
    const float* wr = w + (size_t)o * IN_F + g * 16;
    uint32_t wq[2][16];
    #pragma unroll
    for (int j = 0; j < 16; ++j) {
        float wv = wr[j];
        float wp = rintf(fmaxf(wv, 0.0f) * 4096.0f);
        float wn = rintf(fmaxf(-wv, 0.0f) * 4096.0f);
        wq[0][j] = (uint32_t)fminf(wp, 65535.0f);
        wq[1][j] = (uint32_t)fminf(wn, 65535.0f);
    }
    uint32_t nzmask = 0;
    #pragma unroll
    for (int sgs = 0; sgs < 16; ++sgs) {
        int sg = sgs >> 3, sh = 14 - 2 * (sgs & 7);
        uint32_t dw[4], nz = 0;
        #pragma unroll
        for (int q = 0; q < 4; ++q) {
            uint32_t d = 0;
            #pragma unroll
            for (int j = 0; j < 4; ++j)
                d |= ((wq[sg][q * 4 + j] >> sh) & 3u) << (8 * j);
            dw[q] = d;
            nz |= d;
        }
        *(uint4*)(Bp + (size_t)(g * NCOL + sgs * 1024 + o) * 16) =
            make_uint4(dw[0], dw[1], dw[2], dw[3]);
        nzmask |= (nz ? 1u : 0u) << sgs;
    }
    int r = g >> 2, ob = o >> 7;                    // wave-uniform
    #pragma unroll
    for (int sgs = 0; sgs < 16; ++sgs) {
        int any = __any((int)((nzmask >> sgs) & 1u));
        if (any && (threadIdx.x & 63) == 0)
            atomicOr(&flags[sgs * 8 + ob], 1u << r);
    }
}

// ---------------------------------------------------------------------------
// Main.  blockIdx.x -> idx-th nonzero (sgs,ob) via ballot/popcount scan of
// the 128 flag words (deterministic, ~20 instrs); idx >= count exits.
// No LDS; A fragments are coalesced global loads from fragment-ordered Ap2.
// Epilogue: magic-constant rndne (bit-identical to rintf, ties-to-even) in
// v2f pairs for v_pk_* formation.  ADC bits identical to R1-R4.
// ---------------------------------------------------------------------------
__global__ __launch_bounds__(256, 4) void cim_mfma(
    const uint8_t* __restrict__ Ap2, const uint8_t* __restrict__ Bp,
    const uint32_t* __restrict__ flags, float* __restrict__ part)
{
    const float MAG = 12582912.0f;                  // 2^23 + 2^22
    int tid = threadIdx.x, wid = tid >> 6, l = tid & 63, h2 = l >> 5;

    // ---- worklist: map blockIdx.x to the idx-th nonzero (sgs,ob) ----
    uint32_t f0 = flags[l], f1 = flags[64 + l];
    unsigned long long m0 = __ballot(f0 != 0);
    unsigned long long m1 = __ballot(f1 != 0);
    int n0 = __popcll(m0);
    int total = n0 + __popcll(m1);
    int idx = blockIdx.x;
    if (idx >= total) return;
    unsigned long long lt = (1ULL << l) - 1;
    bool own0 = ((m0 >> l) & 1) && (__popcll(m0 & lt) == idx);
    bool own1 = ((m1 >> l) & 1) && (n0 + __popcll(m1 & lt) == idx);
    unsigned long long s0 = __ballot(own0);
    unsigned long long s1 = __ballot(own1);
    int p = s0 ? __builtin_ctzll(s0) : (64 + __builtin_ctzll(s1));
    int sgs = p >> 3, ob = p & 7;
    uint32_t fb = flags[p];

    int y = blockIdx.y;
    int s = sgs & 7, sg = sgs >> 3;
    int col = sgs * 1024 + ob * 128 + wid * 32 + (l & 31);
    float clane = ldexpf(192.0f / 255.0f, 14 - 2 * s);   // step * 4^(7-s)
    if (sg) clane = -clane;

    v2f acc2[8];
    #pragma unroll
    for (int i = 0; i < 8; ++i) acc2[i] = (v2f)0.0f;
    v16i zero;
    #pragma unroll
    for (int i = 0; i < 16; ++i) zero[i] = 0;

    for (int r = 0; r < RT; ++r) {
        if (!((fb >> r) & 1u)) continue;            // uniform skip, exact

        v4i bf0 = *(const v4i*)(Bp + ((size_t)(r * 4 + h2)     * NCOL + col) * 16);
        v4i bf1 = *(const v4i*)(Bp + ((size_t)(r * 4 + 2 + h2) * NCOL + col) * 16);

        const uint8_t* abase = Ap2 + (size_t)(r * 2 * 8 + y) * 1024 + l * 16;
        #pragma unroll 4
        for (int t = 0; t < STN; ++t) {
            const uint8_t* ap = abase + (size_t)t * (RT * 2 * 8 * 1024);
            v4i af0 = *(const v4i*)ap;              // coalesced 1KB/wave
            v4i af1 = *(const v4i*)(ap + 8 * 1024);
            v16i c = __builtin_amdgcn_mfma_i32_32x32x32_i8(af0, bf0, zero, 0, 0, 0);
            c      = __builtin_amdgcn_mfma_i32_32x32x32_i8(af1, bf1, c,    0, 0, 0);
            float wt = (t == 15) ? -32768.0f : (float)(1 << t);
            float cw = clane * wt;                  // exact pow2 scale
            #pragma unroll
            for (int i = 0; i < 8; ++i) {
                v2f af; af.x = (float)c[2 * i]; af.y = (float)c[2 * i + 1];
                v2f tq;
                tq.x = fmaf(af.x, 1.328125f, MAG);  // product exact; add rounds
                tq.y = fmaf(af.y, 1.328125f, MAG);  //   half-even == rintf
                v2f qf = tq - MAG;                  // Sterbenz-exact
                acc2[i].x = fmaf(qf.x, cw, acc2[i].x);
                acc2[i].y = fmaf(qf.y, cw, acc2[i].y);
            }
        }
    }

    int o = ob * 128 + wid * 32 + (l & 31);
    #pragma unroll
    for (int i = 0; i < 16; ++i) {
        int b = y * 32 + (i & 3) + 8 * (i >> 2) + 4 * h2;   // C/D row map
        float v = (i & 1) ? acc2[i >> 1].y : acc2[i >> 1].x;
        part[((size_t)sgs * BATCH + b) * OUT_F + o] = v;
    }
}

// ---------------------------------------------------------------------------
// Final reduce: sums only flagged (sgs,ob) Part slots (unflagged slots were
// never written; their exact contribution is 0).
// ---------------------------------------------------------------------------
__global__ __launch_bounds__(256) void reduce_out(
    const float* __restrict__ part, const uint32_t* __restrict__ flags,
    const float* __restrict__ bias, float* __restrict__ out)
{
    int idx = blockIdx.x * 256 + threadIdx.x;
    int o = idx & (OUT_F - 1), b = idx >> 10;
    int ob = o >> 7;
    float ov = 0.0f;
    #pragma unroll
    for (int sgs = 0; sgs < 16; ++sgs) {
        if (flags[sgs * 8 + ob])
            ov += part[((size_t)sgs * BATCH + b) * OUT_F + o];
    }
    ov *= 0x1p-24f;
    float q = rintf(ov * 4096.0f);
    q = fminf(fmaxf(q, -32768.0f), 32767.0f);
    out[idx] = q * 0x1p-12f + bias[o];
}

// ---------------------------------------------------------------------------
extern "C" void kernel_launch(void* const* d_in, const int* in_sizes, int n_in,
                              void* d_out, int out_size, void* d_ws, size_t ws_size,
                              hipStream_t stream) {
    const float* x    = (const float*)d_in[0];
    const float* w    = (const float*)d_in[1];
    const float* bias = (const float*)d_in[2];
    float* out = (float*)d_out;

    uint8_t*  Ap2   = (uint8_t*)d_ws;
    uint8_t*  Bp    = Ap2 + AP_SZ;
    float*    Part  = (float*)(Bp + BP_SZ);
    uint32_t* flags = (uint32_t*)((uint8_t*)Part + PART_SZ);

    hipLaunchKernelGGL(pack_A, dim3(64),  dim3(256), 0, stream, x, Ap2, flags);
    hipLaunchKernelGGL(pack_B, dim3(256), dim3(256), 0, stream, w, Bp, flags);
    hipLaunchKernelGGL(cim_mfma, dim3(128, 8), dim3(256), 0, stream,
                       Ap2, Bp, flags, Part);
    hipLaunchKernelGGL(reduce_out, dim3(BATCH * OUT_F / 256), dim3(256), 0, stream,
                       Part, flags, bias, out);
}